// Round 7
// baseline (716.343 us; speedup 1.0000x reference)
//
#include <hip/hip_runtime.h>
#include <cmath>

#define N_NODES 50000
#define N_EDGES 800000
#define D_IN    128
#define D_HID   256
#define D_OUT   47
#define BN_EPS  1e-5f
#define SCAN_NBLK ((N_NODES + 255) / 256)   // 196

typedef __attribute__((ext_vector_type(8))) short bf16x8;
typedef __attribute__((ext_vector_type(4))) float floatx4;
typedef unsigned short u16;

__device__ __forceinline__ short f2bf(float f) {          // legacy (short)
    unsigned u = __float_as_uint(f);
    u += 0x7fff + ((u >> 16) & 1);
    return (short)(u >> 16);
}
__device__ __forceinline__ u16 f2bf_u(float f) {
    unsigned u = __float_as_uint(f);
    u += 0x7fff + ((u >> 16) & 1);
    return (u16)(u >> 16);
}
__device__ __forceinline__ float bf2f(u16 h) {
    return __uint_as_float(((unsigned)h) << 16);
}

// ---------------------------------------------------------------------------
// edge_index layout detection (int64 vs int32)
// ---------------------------------------------------------------------------
__global__ void detect_idx_kernel(const int* __restrict__ ei, int* __restrict__ flag) {
    __shared__ int any_nonzero;
    if (threadIdx.x == 0) any_nonzero = 0;
    __syncthreads();
    int v = ei[2 * threadIdx.x + 1];
    if (v != 0) atomicAdd(&any_nonzero, 1);
    __syncthreads();
    if (threadIdx.x == 0) *flag = (any_nonzero == 0) ? 1 : 0;
}

__device__ __forceinline__ int load_edge(const int* __restrict__ ei, int e, int which, int is64) {
    if (is64) return ei[2 * ((long long)which * N_EDGES + e)];
    return ei[(long long)which * N_EDGES + e];
}

// ---------------------------------------------------------------------------
// CSR build
// ---------------------------------------------------------------------------
__global__ void count_deg_kernel(const int* __restrict__ ei, const int* __restrict__ flag,
                                 int* __restrict__ degi) {
    int e = blockIdx.x * blockDim.x + threadIdx.x;
    if (e >= N_EDGES) return;
    int is64 = *flag;
    atomicAdd(&degi[load_edge(ei, e, 1, is64)], 1);
}

__global__ __launch_bounds__(256) void block_sum_kernel(const int* __restrict__ degi,
                                                        int* __restrict__ bsum) {
    const int i = blockIdx.x * 256 + threadIdx.x;
    int v = (i < N_NODES) ? degi[i] : 0;
#pragma unroll
    for (int off = 32; off > 0; off >>= 1) v += __shfl_down(v, off);
    __shared__ int sh[4];
    if ((threadIdx.x & 63) == 0) sh[threadIdx.x >> 6] = v;
    __syncthreads();
    if (threadIdx.x == 0) bsum[blockIdx.x] = sh[0] + sh[1] + sh[2] + sh[3];
}

__global__ __launch_bounds__(256) void scan_bsums_kernel(int* __restrict__ bsum,
                                                         int* __restrict__ row_ptr) {
    const int t = threadIdx.x;
    __shared__ int sh[256];
    int v = (t < SCAN_NBLK) ? bsum[t] : 0;
    sh[t] = v;
    __syncthreads();
#pragma unroll
    for (int off = 1; off < 256; off <<= 1) {
        int u = (t >= off) ? sh[t - off] : 0;
        __syncthreads();
        sh[t] += u;
        __syncthreads();
    }
    if (t < SCAN_NBLK) bsum[t] = sh[t] - v;
    if (t == 255) row_ptr[N_NODES] = sh[255];
}

__global__ __launch_bounds__(256) void fill_rowptr_kernel(const int* __restrict__ degi,
                                                          const int* __restrict__ bsum,
                                                          int* __restrict__ row_ptr,
                                                          int* __restrict__ cursor,
                                                          float* __restrict__ invd) {
    const int t = threadIdx.x;
    const int i = blockIdx.x * 256 + t;
    __shared__ int sh[256];
    int d = (i < N_NODES) ? degi[i] : 0;
    sh[t] = d;
    __syncthreads();
#pragma unroll
    for (int off = 1; off < 256; off <<= 1) {
        int u = (t >= off) ? sh[t - off] : 0;
        __syncthreads();
        sh[t] += u;
        __syncthreads();
    }
    if (i < N_NODES) {
        const int pos = bsum[blockIdx.x] + sh[t] - d;
        row_ptr[i] = pos;
        cursor[i]  = pos;
        invd[i]    = 1.0f / fmaxf((float)d, 1.0f);
    }
}

__global__ void fill_csr_kernel(const int* __restrict__ ei, const int* __restrict__ flag,
                                int* __restrict__ cursor, int* __restrict__ ssrc) {
    int e = blockIdx.x * blockDim.x + threadIdx.x;
    if (e >= N_EDGES) return;
    int is64 = *flag;
    int s = load_edge(ei, e, 0, is64);
    int d = load_edge(ei, e, 1, is64);
    int pos = atomicAdd(&cursor[d], 1);
    ssrc[pos] = s;
}

// ===========================================================================
// FULL (bf16-direct) path kernels
// ===========================================================================

// x (fp32) -> xb (bf16), N*128 elems
__global__ void convert_xb_kernel(const float* __restrict__ x, u16* __restrict__ xb) {
    const int n4 = N_NODES * D_IN / 4;
    int i = blockIdx.x * 256 + threadIdx.x;
    if (i >= n4) return;
    float4 v = ((const float4*)x)[i];
    ushort4 o;
    o.x = f2bf_u(v.x); o.y = f2bf_u(v.y); o.z = f2bf_u(v.z); o.w = f2bf_u(v.w);
    ((ushort4*)xb)[i] = o;
}

// all weights -> bf16, transposed to [col][k]; WT3 = [W3_l | W3_r | 0pad] (128x256)
__global__ void build_wt_kernel(const float* __restrict__ W1l, const float* __restrict__ W1r,
                                const float* __restrict__ W2l, const float* __restrict__ W2r,
                                const float* __restrict__ W3l, const float* __restrict__ W3r,
                                u16* __restrict__ wt1l, u16* __restrict__ wt1r,
                                u16* __restrict__ wt2l, u16* __restrict__ wt2r,
                                u16* __restrict__ wt3) {
    int idx = blockIdx.x * 256 + threadIdx.x;
    if (idx < 65536) {                       // WT1l / WT1r : 256 cols x 128 k
        int seg = idx >> 15, d = idx & 32767;
        int c = d >> 7, k = d & 127;
        const float* W = seg ? W1r : W1l;
        u16* WT = seg ? wt1r : wt1l;
        WT[d] = f2bf_u(W[k * 256 + c]);
    } else if (idx < 196608) {               // WT2l / WT2r : 256 cols x 256 k
        int d = idx - 65536;
        int seg = d >> 16; d &= 65535;
        int c = d >> 8, k = d & 255;
        const float* W = seg ? W2r : W2l;
        u16* WT = seg ? wt2r : wt2l;
        WT[d] = f2bf_u(W[k * 256 + c]);
    } else if (idx < 229376) {               // WT3 : 128 cols x 256 k, zero-padded
        int d = idx - 196608;
        int c = d >> 8, k = d & 255;
        float v = 0.f;
        if (c < 47)      v = W3l[k * 47 + c];
        else if (c < 94) v = W3r[k * 47 + (c - 47)];
        wt3[d] = f2bf_u(v);
    }
}

// CSR gather-mean over bf16 rows: one wave per node
template <int CC>
__global__ __launch_bounds__(256) void gather_mean_bf(
    const u16* __restrict__ Xb, const int* __restrict__ rp,
    const int* __restrict__ ssrc, const float* __restrict__ invd,
    u16* __restrict__ agg)
{
    const int w = (blockIdx.x * 256 + threadIdx.x) >> 6;
    const int lane = threadIdx.x & 63;
    if (w >= N_NODES) return;
    const int start = rp[w], end = rp[w + 1];
    const float sc = invd[w];

    if constexpr (CC == 256) {
        const u16* base = Xb + lane * 4;
        float4 a = make_float4(0.f, 0.f, 0.f, 0.f);
        int e = start;
        for (; e + 1 < end; e += 2) {
            const ushort4 v0 = *(const ushort4*)(base + (size_t)ssrc[e] * 256);
            const ushort4 v1 = *(const ushort4*)(base + (size_t)ssrc[e + 1] * 256);
            a.x += bf2f(v0.x) + bf2f(v1.x); a.y += bf2f(v0.y) + bf2f(v1.y);
            a.z += bf2f(v0.z) + bf2f(v1.z); a.w += bf2f(v0.w) + bf2f(v1.w);
        }
        if (e < end) {
            const ushort4 v = *(const ushort4*)(base + (size_t)ssrc[e] * 256);
            a.x += bf2f(v.x); a.y += bf2f(v.y); a.z += bf2f(v.z); a.w += bf2f(v.w);
        }
        ushort4 o;
        o.x = f2bf_u(a.x * sc); o.y = f2bf_u(a.y * sc);
        o.z = f2bf_u(a.z * sc); o.w = f2bf_u(a.w * sc);
        *(ushort4*)(agg + (size_t)w * 256 + lane * 4) = o;
    } else {  // CC == 128
        const u16* base = Xb + lane * 2;
        float2 a = make_float2(0.f, 0.f);
        int e = start;
        for (; e + 1 < end; e += 2) {
            const ushort2 v0 = *(const ushort2*)(base + (size_t)ssrc[e] * 128);
            const ushort2 v1 = *(const ushort2*)(base + (size_t)ssrc[e + 1] * 128);
            a.x += bf2f(v0.x) + bf2f(v1.x); a.y += bf2f(v0.y) + bf2f(v1.y);
        }
        if (e < end) {
            const ushort2 v = *(const ushort2*)(base + (size_t)ssrc[e] * 128);
            a.x += bf2f(v.x); a.y += bf2f(v.y);
        }
        ushort2 o;
        o.x = f2bf_u(a.x * sc); o.y = f2bf_u(a.y * sc);
        *(ushort2*)(agg + (size_t)w * 128 + lane * 2) = o;
    }
}

// ---------------------------------------------------------------------------
// Direct-from-global bf16 MFMA GEMM (no LDS, no barriers):
//   C = A0@WT0^T (+ A1@WT1^T) [+bias][+BN+ReLU], optional bf16 shadow Cb.
//   split>0: cols<split -> C (no bias); split<=col<2*split -> C2 + bias.
// Tile 64x128: 4 waves x 16 rows, 8 col-tiles/wave; grid 2x more blocks than
// the R6 128x128 tile (782 -> 1564 for M=256) to fix the 33% occupancy bound.
// A row-major bf16 [N][K]; WT bf16 [col][K]. K mult of 32.
// ---------------------------------------------------------------------------
__global__ __launch_bounds__(256, 4) void mfma_direct(
    const u16* __restrict__ A0, int K0, const u16* __restrict__ WT0,
    const u16* __restrict__ A1, int K1, const u16* __restrict__ WT1,
    const float* __restrict__ bias,
    const float* __restrict__ gamma, const float* __restrict__ beta,
    const float* __restrict__ mean, const float* __restrict__ var,
    float* __restrict__ C, int M, int do_bias, int bn_relu,
    u16* __restrict__ Cb, float* __restrict__ C2, int split)
{
    const int t = threadIdx.x;
    const int wv = t >> 6, lane = t & 63;
    const int lr = lane & 15, quad = lane >> 4;
    const int row0 = blockIdx.y * 64;
    const int col0 = blockIdx.x * 128;

    floatx4 acc[8];
#pragma unroll
    for (int c = 0; c < 8; ++c) acc[c] = (floatx4){0.f, 0.f, 0.f, 0.f};

    int rr = row0 + wv * 16 + lr;
    const int rowa = (rr < N_NODES) ? rr : (N_NODES - 1);

    for (int pass = 0; pass < 2; ++pass) {
        const u16* __restrict__ A = pass ? A1 : A0;
        if (A == nullptr) break;
        const u16* __restrict__ WT = pass ? WT1 : WT0;
        const int K = pass ? K1 : K0;

        const u16* pa = A + (size_t)rowa * K + quad * 8;
        const u16* pb = WT + (size_t)(col0 + lr) * K + quad * 8;
        const size_t cstride = (size_t)16 * K;   // elements between col-tiles

#pragma unroll 2
        for (int k0 = 0; k0 < K; k0 += 32) {
            bf16x8 a = *(const bf16x8*)(pa + k0);
            bf16x8 b[8];
#pragma unroll
            for (int c = 0; c < 8; ++c)
                b[c] = *(const bf16x8*)(pb + c * cstride + k0);
#pragma unroll
            for (int c = 0; c < 8; ++c)
                acc[c] = __builtin_amdgcn_mfma_f32_16x16x32_bf16(a, b[c], acc[c], 0, 0, 0);
        }
    }

    // epilogue (C/D: col=lr, row=quad*4+g)
#pragma unroll
    for (int g = 0; g < 4; ++g) {
        const int row = row0 + wv * 16 + quad * 4 + g;
        if (row >= N_NODES) continue;
#pragma unroll
        for (int c = 0; c < 8; ++c) {
            const int col = col0 + c * 16 + lr;
            float v = acc[c][g];
            if (split > 0) {
                if (col < split) {
                    C[(size_t)row * split + col] = v;
                } else if (col < 2 * split) {
                    C2[(size_t)row * split + (col - split)] = v + bias[col - split];
                }
            } else {
                if (col >= M) continue;
                if (do_bias) v += bias[col];
                if (bn_relu) {
                    v = (v - mean[col]) * (gamma[col] * rsqrtf(var[col] + BN_EPS)) + beta[col];
                    v = fmaxf(v, 0.0f);
                }
                const size_t off = (size_t)row * M + col;
                C[off] = v;
                if (Cb) Cb[off] = f2bf_u(v);
            }
        }
    }
}

// ===========================================================================
// SAFE path kernels (R5, proven)
// ===========================================================================
template <int CC>
__global__ __launch_bounds__(256) void gather_mean(
    const float* __restrict__ X, int ldx,
    const int* __restrict__ rp, const int* __restrict__ ssrc,
    const float* __restrict__ invd, float* __restrict__ agg)
{
    const long long gid = (long long)blockIdx.x * blockDim.x + threadIdx.x;
    const int w = (int)(gid >> 6);
    const int lane = threadIdx.x & 63;
    if (w >= N_NODES) return;
    const int start = rp[w], end = rp[w + 1];
    const float sc = invd[w];

    if constexpr (CC == 256) {
        const float* base = X + lane * 4;
        float4 a = make_float4(0.f, 0.f, 0.f, 0.f);
        int e = start;
        for (; e + 1 < end; e += 2) {
            int s0 = ssrc[e], s1 = ssrc[e + 1];
            float4 v0 = *(const float4*)(base + (long long)s0 * ldx);
            float4 v1 = *(const float4*)(base + (long long)s1 * ldx);
            a.x += v0.x + v1.x; a.y += v0.y + v1.y;
            a.z += v0.z + v1.z; a.w += v0.w + v1.w;
        }
        if (e < end) {
            float4 v = *(const float4*)(base + (long long)ssrc[e] * ldx);
            a.x += v.x; a.y += v.y; a.z += v.z; a.w += v.w;
        }
        float4 o = make_float4(a.x * sc, a.y * sc, a.z * sc, a.w * sc);
        *(float4*)(agg + (long long)w * 256 + lane * 4) = o;
    } else {
        const float* base = X + lane * 2;
        float2 a = make_float2(0.f, 0.f);
        int e = start;
        for (; e + 1 < end; e += 2) {
            int s0 = ssrc[e], s1 = ssrc[e + 1];
            float2 v0 = *(const float2*)(base + (long long)s0 * ldx);
            float2 v1 = *(const float2*)(base + (long long)s1 * ldx);
            a.x += v0.x + v1.x; a.y += v0.y + v1.y;
        }
        if (e < end) {
            float2 v = *(const float2*)(base + (long long)ssrc[e] * ldx);
            a.x += v.x; a.y += v.y;
        }
        float2 o = make_float2(a.x * sc, a.y * sc);
        *(float2*)(agg + (long long)w * 128 + lane * 2) = o;
    }
}

#define GBM 128
#define GBN 64
#define GBK 32
#define LDA 40
#define LDB 40

__global__ __launch_bounds__(256) void mfma_gemm(
    const float* __restrict__ A0, const float* __restrict__ B0, int K0,
    const float* __restrict__ A1, const float* __restrict__ B1, int K1,
    const float* __restrict__ bias,
    const float* __restrict__ gamma, const float* __restrict__ beta,
    const float* __restrict__ mean, const float* __restrict__ var,
    float* __restrict__ C, int M, int do_bias, int bn_relu)
{
    __shared__ short As[GBM * LDA];
    __shared__ short Bs[GBN * LDB];

    const int t = threadIdx.x;
    const int wv = t >> 6;
    const int lane = t & 63;
    const int row0 = blockIdx.y * GBM;
    const int col0 = blockIdx.x * GBN;

    const int lr = lane & 15;
    const int lk = (lane >> 4) * 8;

    floatx4 acc[2][4];
#pragma unroll
    for (int r = 0; r < 2; ++r)
#pragma unroll
        for (int c = 0; c < 4; ++c) acc[r][c] = (floatx4){0.f, 0.f, 0.f, 0.f};

    const int arow = t >> 3;
    const int akc  = (t & 7) * 4;
    const int bkr  = t >> 4;
    const int bcc  = (t & 15) * 4;

    for (int pass = 0; pass < 2; ++pass) {
        if (pass == 1 && A1 == nullptr) break;
        const float* __restrict__ A = pass ? A1 : A0;
        const float* __restrict__ B = pass ? B1 : B0;
        const int K = pass ? K1 : K0;

        for (int k0 = 0; k0 < K; k0 += GBK) {
            __syncthreads();
#pragma unroll
            for (int i = 0; i < 4; ++i) {
                const int lrow = arow + i * 32;
                const int grow = row0 + lrow;
                float4 v = make_float4(0.f, 0.f, 0.f, 0.f);
                if (grow < N_NODES)
                    v = *(const float4*)(A + (long long)grow * K + k0 + akc);
                short4 sv;
                sv.x = f2bf(v.x); sv.y = f2bf(v.y);
                sv.z = f2bf(v.z); sv.w = f2bf(v.w);
                *(short4*)(&As[lrow * LDA + akc]) = sv;
            }
#pragma unroll
            for (int i = 0; i < 2; ++i) {
                const int k = bkr + i * 16;
                const int gc = col0 + bcc;
                float4 v;
                if (gc + 3 < M) {
                    v = *(const float4*)(B + (long long)(k0 + k) * M + gc);
                } else {
                    v.x = (gc + 0 < M) ? B[(long long)(k0 + k) * M + gc + 0] : 0.f;
                    v.y = (gc + 1 < M) ? B[(long long)(k0 + k) * M + gc + 1] : 0.f;
                    v.z = (gc + 2 < M) ? B[(long long)(k0 + k) * M + gc + 2] : 0.f;
                    v.w = (gc + 3 < M) ? B[(long long)(k0 + k) * M + gc + 3] : 0.f;
                }
                Bs[(bcc + 0) * LDB + k] = f2bf(v.x);
                Bs[(bcc + 1) * LDB + k] = f2bf(v.y);
                Bs[(bcc + 2) * LDB + k] = f2bf(v.z);
                Bs[(bcc + 3) * LDB + k] = f2bf(v.w);
            }
            __syncthreads();

            bf16x8 af[2], bfr[4];
#pragma unroll
            for (int r = 0; r < 2; ++r)
                af[r] = *(const bf16x8*)(&As[(wv * 32 + r * 16 + lr) * LDA + lk]);
#pragma unroll
            for (int c = 0; c < 4; ++c)
                bfr[c] = *(const bf16x8*)(&Bs[(c * 16 + lr) * LDB + lk]);
#pragma unroll
            for (int r = 0; r < 2; ++r)
#pragma unroll
                for (int c = 0; c < 4; ++c)
                    acc[r][c] = __builtin_amdgcn_mfma_f32_16x16x32_bf16(
                        af[r], bfr[c], acc[r][c], 0, 0, 0);
        }
    }

#pragma unroll
    for (int r = 0; r < 2; ++r) {
#pragma unroll
        for (int g = 0; g < 4; ++g) {
            const int row = row0 + wv * 32 + r * 16 + (lane >> 4) * 4 + g;
            if (row >= N_NODES) continue;
#pragma unroll
            for (int c = 0; c < 4; ++c) {
                const int col = col0 + c * 16 + lr;
                if (col >= M) continue;
                float v = acc[r][c][g];
                if (do_bias) v += bias[col];
                if (bn_relu) {
                    v = (v - mean[col]) * (gamma[col] * rsqrtf(var[col] + BN_EPS)) + beta[col];
                    v = fmaxf(v, 0.0f);
                }
                C[(long long)row * M + col] = v;
            }
        }
    }
}

// ---------------------------------------------------------------------------
// shared epilogue kernels
// ---------------------------------------------------------------------------
__global__ __launch_bounds__(256) void gather_add_out(
    const float* __restrict__ U, const int* __restrict__ rp,
    const int* __restrict__ ssrc, const float* __restrict__ invd,
    float* __restrict__ z)
{
    const int w = (blockIdx.x * 256 + threadIdx.x) >> 6;
    const int lane = threadIdx.x & 63;
    if (w >= N_NODES) return;
    const int start = rp[w], end = rp[w + 1];
    float a = 0.f;
    for (int e = start; e < end; ++e) {
        int s = ssrc[e];
        if (lane < D_OUT) a += U[(long long)s * D_OUT + lane];
    }
    if (lane < D_OUT) z[(long long)w * D_OUT + lane] += a * invd[w];
}

__global__ void log_softmax_kernel(const float* __restrict__ z, float* __restrict__ y) {
    const int gtid = blockIdx.x * blockDim.x + threadIdx.x;
    const int row = gtid >> 6;
    const int lane = threadIdx.x & 63;
    if (row >= N_NODES) return;

    const float* zr = z + (long long)row * D_OUT;
    float v = (lane < D_OUT) ? zr[lane] : -INFINITY;

    float m = v;
#pragma unroll
    for (int off = 32; off > 0; off >>= 1) m = fmaxf(m, __shfl_down(m, off));
    m = __shfl(m, 0);

    float ev = (lane < D_OUT) ? expf(v - m) : 0.0f;
    float s = ev;
#pragma unroll
    for (int off = 32; off > 0; off >>= 1) s += __shfl_down(s, off);
    s = __shfl(s, 0);

    if (lane < D_OUT) y[(long long)row * D_OUT + lane] = v - m - logf(s);
}

// ---------------------------------------------------------------------------
// launch
// ---------------------------------------------------------------------------
extern "C" void kernel_launch(void* const* d_in, const int* in_sizes, int n_in,
                              void* d_out, int out_size, void* d_ws, size_t ws_size,
                              hipStream_t stream) {
    const float* x     = (const float*)d_in[0];
    const int*   ei    = (const int*)d_in[1];
    const float* W1_l  = (const float*)d_in[2];
    const float* b1    = (const float*)d_in[3];
    const float* W1_r  = (const float*)d_in[4];
    const float* bn1_g = (const float*)d_in[5];
    const float* bn1_b = (const float*)d_in[6];
    const float* bn1_m = (const float*)d_in[7];
    const float* bn1_v = (const float*)d_in[8];
    const float* W2_l  = (const float*)d_in[9];
    const float* b2    = (const float*)d_in[10];
    const float* W2_r  = (const float*)d_in[11];
    const float* bn2_g = (const float*)d_in[12];
    const float* bn2_b = (const float*)d_in[13];
    const float* bn2_m = (const float*)d_in[14];
    const float* bn2_v = (const float*)d_in[15];
    const float* W3_l  = (const float*)d_in[16];
    const float* b3    = (const float*)d_in[17];
    const float* W3_r  = (const float*)d_in[18];

    // --- common workspace (CSR) ---
    char* ws = (char*)d_ws;
    int*   degi    = (int*)(ws + 0);
    int*   row_ptr = (int*)(ws + 200064);
    int*   cursor  = (int*)(ws + 400128);
    float* invd    = (float*)(ws + 600192);
    int*   flag    = (int*)(ws + 800256);
    int*   bsum    = (int*)(ws + 800320);
    int*   ssrc    = (int*)(ws + 801152);          // 3.2 MB -> ends 4,001,152

    // d_out layout: z [N*47] | y_pred [N*47] | S1 [N*256] | S2 [N*256]
    float* z     = (float*)d_out;
    float* ypred = z + (long long)N_NODES * D_OUT;
    float* S1    = ypred + (long long)N_NODES * D_OUT;
    float* S2    = S1 + (long long)N_NODES * D_HID;

    // --- CSR build (shared) ---
    detect_idx_kernel<<<1, 256, 0, stream>>>(ei, flag);
    hipMemsetAsync(degi, 0, N_NODES * sizeof(int), stream);
    count_deg_kernel<<<(N_EDGES + 255) / 256, 256, 0, stream>>>(ei, flag, degi);
    block_sum_kernel<<<SCAN_NBLK, 256, 0, stream>>>(degi, bsum);
    scan_bsums_kernel<<<1, 256, 0, stream>>>(bsum, row_ptr);
    fill_rowptr_kernel<<<SCAN_NBLK, 256, 0, stream>>>(degi, bsum, row_ptr, cursor, invd);
    fill_csr_kernel<<<(N_EDGES + 255) / 256, 256, 0, stream>>>(ei, flag, cursor, ssrc);

    const int gblocks = (N_NODES * 64 + 255) / 256;

    // FULL bf16-direct plan needs 94,059,904 B of ws
    if (ws_size >= 94059904ULL) {
        u16*   wt1l = (u16*)(ws + 4001152);
        u16*   wt1r = (u16*)(ws + 4066688);
        u16*   wt2l = (u16*)(ws + 4132224);
        u16*   wt2r = (u16*)(ws + 4263296);
        u16*   wt3  = (u16*)(ws + 4394368);
        u16*   xb   = (u16*)(ws + 4459904);        // N*128 bf16
        u16*   S1b  = (u16*)(ws + 17259904);       // N*256 bf16
        u16*   S2b  = (u16*)(ws + 42859904);       // N*256 bf16
        u16*   agg  = (u16*)(ws + 68459904);       // N*256 bf16 (reused as U fp32)
        float* U    = (float*)agg;

        convert_xb_kernel<<<(N_NODES * D_IN / 4 + 255) / 256, 256, 0, stream>>>(x, xb);
        build_wt_kernel<<<(229376 + 255) / 256, 256, 0, stream>>>(
            W1_l, W1_r, W2_l, W2_r, W3_l, W3_r, wt1l, wt1r, wt2l, wt2r, wt3);

        const dim3 gHid(2, (N_NODES + 63) / 64);   // M=256: 2 x 782 blocks
        const dim3 gOut(1, (N_NODES + 63) / 64);   // M=94 (padded 128): 1 x 782

        // layer 1
        gather_mean_bf<128><<<gblocks, 256, 0, stream>>>(xb, row_ptr, ssrc, invd, agg);
        mfma_direct<<<gHid, 256, 0, stream>>>(agg, D_IN, wt1l, xb, D_IN, wt1r,
                                              b1, bn1_g, bn1_b, bn1_m, bn1_v,
                                              S1, D_HID, 1, 1, S1b, nullptr, 0);
        // layer 2
        gather_mean_bf<256><<<gblocks, 256, 0, stream>>>(S1b, row_ptr, ssrc, invd, agg);
        mfma_direct<<<gHid, 256, 0, stream>>>(agg, D_HID, wt2l, S1b, D_HID, wt2r,
                                              b2, bn2_g, bn2_b, bn2_m, bn2_v,
                                              S2, D_HID, 1, 1, S2b, nullptr, 0);
        // layer 3 (fused transform-first: U = S2@W3_l, z = S2@W3_r + b3)
        mfma_direct<<<gOut, 256, 0, stream>>>(S2b, D_HID, wt3, nullptr, 0, nullptr,
                                              b3, nullptr, nullptr, nullptr, nullptr,
                                              U, 94, 0, 0, nullptr, z, D_OUT);
        gather_add_out<<<gblocks, 256, 0, stream>>>(U, row_ptr, ssrc, invd, z);
    } else {
        // SAFE: R5 fp32-LDS pipeline (proven <= 55.2 MB)
        float* aggF = (float*)(ws + 4001152);      // N*256 fp32, ends 55,201,152
        float* U    = aggF;

        const dim3 gHid(D_HID / GBN, (N_NODES + GBM - 1) / GBM);
        const dim3 gOut(1, (N_NODES + GBM - 1) / GBM);

        gather_mean<128><<<gblocks, 256, 0, stream>>>(x, D_IN, row_ptr, ssrc, invd, aggF);
        mfma_gemm<<<gHid, 256, 0, stream>>>(aggF, W1_l, D_IN, x, W1_r, D_IN,
                                            b1, bn1_g, bn1_b, bn1_m, bn1_v,
                                            S1, D_HID, 1, 1);
        gather_mean<256><<<gblocks, 256, 0, stream>>>(S1, D_HID, row_ptr, ssrc, invd, aggF);
        mfma_gemm<<<gHid, 256, 0, stream>>>(aggF, W2_l, D_HID, S1, W2_r, D_HID,
                                            b2, bn2_g, bn2_b, bn2_m, bn2_v,
                                            S2, D_HID, 1, 1);
        mfma_gemm<<<gOut, 256, 0, stream>>>(S2, W3_l, D_HID, nullptr, nullptr, 0,
                                            nullptr, nullptr, nullptr, nullptr, nullptr,
                                            U, D_OUT, 0, 0);
        mfma_gemm<<<gOut, 256, 0, stream>>>(S2, W3_r, D_HID, nullptr, nullptr, 0,
                                            b3, nullptr, nullptr, nullptr, nullptr,
                                            z, D_OUT, 1, 0);
        gather_add_out<<<gblocks, 256, 0, stream>>>(U, row_ptr, ssrc, invd, z);
    }

    log_softmax_kernel<<<gblocks, 256, 0, stream>>>(z, ypred);
}